// Round 9
// baseline (108.513 us; speedup 1.0000x reference)
//
#include <hip/hip_runtime.h>

#define IMG_H 1080
#define IMG_W 1920
#define TILE_W 64
#define TILE_H 4
#define SW 70            // TILE_W + 6
#define SH 10            // TILE_H + 6
#define SP 72            // padded LDS row stride (floats)

// Nonzero iff the 16-bit circular mask has 9 consecutive set bits.
// (Equivalent to reference's 24-bit window test; validated absmax=0 R1-R8.)
__device__ __forceinline__ unsigned det9(unsigned m) {
    unsigned x = m | (m << 16);
    unsigned t = x & (x >> 1);   // run 2
    t &= t >> 2;                 // run 4
    t &= t >> 4;                 // run 8
    t &= x >> 8;                 // run 9
    return t;
}

// m = (m << 1) | (val CMP thr) in exactly 2 VALU (v_cmp + v_addc m+m+carry).
// Separate SGPR carry per chain so dark/bright interleave. Validated R8.
#define STEP_GE(m, sc, val, thr)                                          \
    asm("v_cmp_ge_f32 %1, %2, %3\n\tv_addc_co_u32 %0, %1, %0, %0, %1"     \
        : "+v"(m), "=s"(sc) : "v"(val), "v"(thr))
#define STEP_LE(m, sc, val, thr)                                          \
    asm("v_cmp_le_f32 %1, %2, %3\n\tv_addc_co_u32 %0, %1, %0, %0, %1"     \
        : "+v"(m), "=s"(sc) : "v"(val), "v"(thr))

__global__ __launch_bounds__(256) void fast_score_kernel(const float* __restrict__ img,
                                                         float* __restrict__ out) {
    __shared__ float sm[SH * SP];

    const int n  = blockIdx.z;
    const int x0 = blockIdx.x * TILE_W;
    const int y0 = blockIdx.y * TILE_H;
    const int tid = threadIdx.x;

    const float* in = img + (size_t)n * (IMG_H * IMG_W);
    float* op = out + (size_t)n * (IMG_H * IMG_W);

    // ---- stage 10x70 tile+halo into LDS (replicate-clamped), 700 elems ----
    for (int i = tid; i < SH * SW; i += 256) {
        const int r = i / SW;
        const int c = i - r * SW;
        int gy = min(max(y0 - 3 + r, 0), IMG_H - 1);
        int gx = min(max(x0 - 3 + c, 0), IMG_W - 1);
        sm[r * SP + c] = in[(size_t)gy * IMG_W + gx];
    }
    __syncthreads();

    // ---- 1 px per thread ----
    const int tx = tid & 63;          // 0..63
    const int ty = tid >> 6;          // 0..3
    const float* base = &sm[(ty + 3) * SP + (tx + 3)];   // center address

    constexpr int DY[16] = {0, 1, 2, 3, 3, 3, 2, 1, 0, -1, -2, -3, -3, -3, -2, -1};
    constexpr int DX[16] = {-3, -3, -2, -1, 0, 1, 2, 3, 3, 3, 2, 1, 0, -1, -2, -3};

    const float center = base[0];
    float t[16];
#pragma unroll
    for (int k = 0; k < 16; ++k) {
        t[k] = base[DY[k] * SP + DX[k]];   // static imm offsets off one base
    }

    const float hi = center + 20.0f;
    const float lo = center - 20.0f;
    unsigned dark = 0u, bright = 0u;
    unsigned long long sc0, sc1;
#pragma unroll
    for (int k = 0; k < 16; ++k) {
        STEP_GE(dark,   sc0, t[k], hi);
        STEP_LE(bright, sc1, t[k], lo);
    }

    const float res = (det9(dark) | det9(bright)) ? 1.0f : 0.0f;
    op[(size_t)(y0 + ty) * IMG_W + (x0 + tx)] = res;   // grid covers exactly, no guard
}

extern "C" void kernel_launch(void* const* d_in, const int* in_sizes, int n_in,
                              void* d_out, int out_size, void* d_ws, size_t ws_size,
                              hipStream_t stream) {
    const float* img = (const float*)d_in[0];
    float* out = (float*)d_out;
    const int n_img = in_sizes[0] / (IMG_H * IMG_W);   // = 4
    dim3 grid(IMG_W / TILE_W,    // 30
              IMG_H / TILE_H,    // 270
              n_img);            // 4  -> 32400 blocks
    fast_score_kernel<<<grid, 256, 0, stream>>>(img, out);
}

// Round 10
// 99.265 us; speedup vs baseline: 1.0932x; 1.0932x over previous
//
#include <hip/hip_runtime.h>

#define IMG_H 1080
#define IMG_W 1920

// Nonzero iff the 16-bit circular mask has 9 consecutive set bits.
// (Equivalent to reference's 24-bit window test; validated absmax=0 R1-R9.)
__device__ __forceinline__ unsigned det9(unsigned m) {
    unsigned x = m | (m << 16);
    unsigned t = x & (x >> 1);   // run 2
    t &= t >> 2;                 // run 4
    t &= t >> 4;                 // run 8
    t &= x >> 8;                 // run 9
    return t;
}

// m = (m << 1) | (val CMP thr) in exactly 2 VALU (v_cmp + v_addc m+m+carry).
#define STEP_GE(m, sc, val, thr)                                          \
    asm("v_cmp_ge_f32 %1, %2, %3\n\tv_addc_co_u32 %0, %1, %0, %0, %1"     \
        : "+v"(m), "=s"(sc) : "v"(val), "v"(thr))
#define STEP_LE(m, sc, val, thr)                                          \
    asm("v_cmp_le_f32 %1, %2, %3\n\tv_addc_co_u32 %0, %1, %0, %0, %1"     \
        : "+v"(m), "=s"(sc) : "v"(val), "v"(thr))

__global__ __launch_bounds__(256) void fast_score_kernel(const float* __restrict__ img,
                                                         float* __restrict__ out) {
    const int n  = blockIdx.z;
    const int y  = blockIdx.y;                       // one image row per block
    const int gx = blockIdx.x * 256 + threadIdx.x;   // 0..2047 (loads self-clamp)

    const float* base = img + (size_t)n * (IMG_H * IMG_W);

    // 7 replicate-clamped row pointers — block-uniform => SGPR pairs,
    // taps compile to global_load_dword v, v_off, s[row] (saddr form).
    const float* rp[7];
#pragma unroll
    for (int d = 0; d < 7; ++d) {
        const int ry = min(max(y + d - 3, 0), IMG_H - 1);
        rp[d] = base + (size_t)ry * IMG_W;
    }

    // 7 replicate-clamped column indices (VGPR; v_add + v_med3_i32 each)
    int c[7];
#pragma unroll
    for (int d = 0; d < 7; ++d) {
        c[d] = min(max(gx + d - 3, 0), IMG_W - 1);
    }

    constexpr int DY[16] = {0, 1, 2, 3, 3, 3, 2, 1, 0, -1, -2, -3, -3, -3, -2, -1};
    constexpr int DX[16] = {-3, -3, -2, -1, 0, 1, 2, 3, 3, 3, 2, 1, 0, -1, -2, -3};

    // 17 independent loads, issued back-to-back; single vmcnt drain, no barrier.
    const float center = rp[3][c[3]];
    float t[16];
#pragma unroll
    for (int k = 0; k < 16; ++k) {
        t[k] = rp[DY[k] + 3][c[DX[k] + 3]];
    }

    const float hi = center + 20.0f;
    const float lo = center - 20.0f;
    unsigned dark = 0u, bright = 0u;
    unsigned long long sc0, sc1;
#pragma unroll
    for (int k = 0; k < 16; ++k) {
        STEP_GE(dark,   sc0, t[k], hi);
        STEP_LE(bright, sc1, t[k], lo);
    }

    const float res = (det9(dark) | det9(bright)) ? 1.0f : 0.0f;
    if (gx < IMG_W) {
        out[(size_t)n * (IMG_H * IMG_W) + (size_t)y * IMG_W + gx] = res;
    }
}

extern "C" void kernel_launch(void* const* d_in, const int* in_sizes, int n_in,
                              void* d_out, int out_size, void* d_ws, size_t ws_size,
                              hipStream_t stream) {
    const float* img = (const float*)d_in[0];
    float* out = (float*)d_out;
    const int n_img = in_sizes[0] / (IMG_H * IMG_W);   // = 4
    dim3 grid((IMG_W + 255) / 256,   // 8
              IMG_H,                 // 1080
              n_img);                // 4  -> 34560 blocks
    fast_score_kernel<<<grid, 256, 0, stream>>>(img, out);
}